// Round 1
// baseline (452.155 us; speedup 1.0000x reference)
//
#include <hip/hip_runtime.h>
#include <math.h>

// Weighted Procrustes (Kabsch) for B=8192 batches of N=2048 points.
// One 256-thread block per batch: streaming float4 reduction of 16 sums,
// then Horn quaternion method (4x4 Jacobi eigen) on thread 0.

constexpr int kB = 8192;
constexpr int kN = 2048;
constexpr float kEps = 1e-5f;

__global__ __launch_bounds__(256) void wproc_kernel(
    const float* __restrict__ src,
    const float* __restrict__ src_corr,
    const float* __restrict__ weights,
    float* __restrict__ out)
{
    const int b = blockIdx.x;
    const float* wrow = weights + (size_t)b * kN;
    const float* arow = src + (size_t)b * 3 * kN;
    const float* brow = src_corr + (size_t)b * 3 * kN;

    // acc layout: [0]=sum w, [1..3]=sum w*a, [4..6]=sum w*b, [7..15]=sum w*a_d*b_e
    float acc[16];
#pragma unroll
    for (int i = 0; i < 16; ++i) acc[i] = 0.f;

    const float4* w4  = reinterpret_cast<const float4*>(wrow);
    const float4* ax4 = reinterpret_cast<const float4*>(arow);
    const float4* ay4 = reinterpret_cast<const float4*>(arow + kN);
    const float4* az4 = reinterpret_cast<const float4*>(arow + 2 * kN);
    const float4* bx4 = reinterpret_cast<const float4*>(brow);
    const float4* by4 = reinterpret_cast<const float4*>(brow + kN);
    const float4* bz4 = reinterpret_cast<const float4*>(brow + 2 * kN);

    for (int i = threadIdx.x; i < kN / 4; i += blockDim.x) {
        float4 w  = w4[i];
        float4 ax = ax4[i], ay = ay4[i], az = az4[i];
        float4 bx = bx4[i], by = by4[i], bz = bz4[i];
        float wc[4]  = {w.x,  w.y,  w.z,  w.w};
        float axc[4] = {ax.x, ax.y, ax.z, ax.w};
        float ayc[4] = {ay.x, ay.y, ay.z, ay.w};
        float azc[4] = {az.x, az.y, az.z, az.w};
        float bxc[4] = {bx.x, bx.y, bx.z, bx.w};
        float byc[4] = {by.x, by.y, by.z, by.w};
        float bzc[4] = {bz.x, bz.y, bz.z, bz.w};
#pragma unroll
        for (int c = 0; c < 4; ++c) {
            float ww  = wc[c];
            float wax = ww * axc[c], way = ww * ayc[c], waz = ww * azc[c];
            float bxx = bxc[c], byy = byc[c], bzz = bzc[c];
            acc[0]  += ww;
            acc[1]  += wax;       acc[2]  += way;       acc[3]  += waz;
            acc[4]  += ww * bxx;  acc[5]  += ww * byy;  acc[6]  += ww * bzz;
            acc[7]  += wax * bxx; acc[8]  += wax * byy; acc[9]  += wax * bzz;
            acc[10] += way * bxx; acc[11] += way * byy; acc[12] += way * bzz;
            acc[13] += waz * bxx; acc[14] += waz * byy; acc[15] += waz * bzz;
        }
    }

    // wave (64-lane) butterfly reduction of all 16 sums
#pragma unroll
    for (int i = 0; i < 16; ++i) {
        float v = acc[i];
        for (int off = 32; off > 0; off >>= 1)
            v += __shfl_down(v, off, 64);
        acc[i] = v;
    }

    __shared__ float red[4][16];
    const int lane = threadIdx.x & 63;
    const int wid  = threadIdx.x >> 6;
    if (lane == 0) {
#pragma unroll
        for (int i = 0; i < 16; ++i) red[wid][i] = acc[i];
    }
    __syncthreads();
    if (threadIdx.x != 0) return;

    float t[16];
#pragma unroll
    for (int i = 0; i < 16; ++i)
        t[i] = red[0][i] + red[1][i] + red[2][i] + red[3][i];

    const float W   = t[0];
    const float inv = 1.f / (W + kEps);
    const float S   = W * inv;           // sum of normalized weights (≈1)
    float ca[3], cb[3];
#pragma unroll
    for (int d = 0; d < 3; ++d) { ca[d] = t[1 + d] * inv; cb[d] = t[4 + d] * inv; }

    // cov[d][e] = Sab[d][e]/denom - ca[d]*cb[e]*(2-S)
    float M[3][3];
    const float f2 = 2.f - S;
#pragma unroll
    for (int d = 0; d < 3; ++d)
#pragma unroll
        for (int e = 0; e < 3; ++e)
            M[d][e] = t[7 + 3 * d + e] * inv - ca[d] * cb[e] * f2;

    // Horn's 4x4 symmetric matrix: max eigenvector = quaternion of optimal R (b ≈ R a)
    const float T  = M[0][0] + M[1][1] + M[2][2];
    const float cx = M[1][2] - M[2][1];
    const float cy = M[2][0] - M[0][2];
    const float cz = M[0][1] - M[1][0];
    float Nm[4][4];
    Nm[0][0] = T;
    Nm[0][1] = Nm[1][0] = cx;
    Nm[0][2] = Nm[2][0] = cy;
    Nm[0][3] = Nm[3][0] = cz;
    Nm[1][1] = 2.f * M[0][0] - T;
    Nm[2][2] = 2.f * M[1][1] - T;
    Nm[3][3] = 2.f * M[2][2] - T;
    Nm[1][2] = Nm[2][1] = M[0][1] + M[1][0];
    Nm[1][3] = Nm[3][1] = M[0][2] + M[2][0];
    Nm[2][3] = Nm[3][2] = M[1][2] + M[2][1];

    float Vv[4][4] = {{1,0,0,0},{0,1,0,0},{0,0,1,0},{0,0,0,1}};
    const int pp[6] = {0,0,0,1,1,2};
    const int qq[6] = {1,2,3,2,3,3};
    for (int sweep = 0; sweep < 6; ++sweep) {
        for (int r = 0; r < 6; ++r) {
            const int p = pp[r], q = qq[r];
            const float apq = Nm[p][q];
            if (fabsf(apq) < 1e-12f) continue;
            const float tau = (Nm[q][q] - Nm[p][p]) / (2.f * apq);
            const float tt  = copysignf(1.f, tau) / (fabsf(tau) + sqrtf(1.f + tau * tau));
            const float c   = 1.f / sqrtf(1.f + tt * tt);
            const float s   = tt * c;
            const float app = Nm[p][p], aqq = Nm[q][q];
            Nm[p][p] = app - tt * apq;
            Nm[q][q] = aqq + tt * apq;
            Nm[p][q] = Nm[q][p] = 0.f;
#pragma unroll
            for (int k = 0; k < 4; ++k) {
                if (k == p || k == q) continue;
                const float akp = Nm[k][p], akq = Nm[k][q];
                Nm[k][p] = Nm[p][k] = c * akp - s * akq;
                Nm[k][q] = Nm[q][k] = s * akp + c * akq;
            }
#pragma unroll
            for (int k = 0; k < 4; ++k) {
                const float vkp = Vv[k][p], vkq = Vv[k][q];
                Vv[k][p] = c * vkp - s * vkq;
                Vv[k][q] = s * vkp + c * vkq;
            }
        }
    }

    int jm = 0;
    for (int j = 1; j < 4; ++j) if (Nm[j][j] > Nm[jm][jm]) jm = j;
    float qw = Vv[0][jm], qx = Vv[1][jm], qy = Vv[2][jm], qz = Vv[3][jm];
    const float nq = 1.f / sqrtf(qw * qw + qx * qx + qy * qy + qz * qz);
    qw *= nq; qx *= nq; qy *= nq; qz *= nq;

    float R[3][3];
    R[0][0] = 1.f - 2.f * (qy * qy + qz * qz);
    R[0][1] = 2.f * (qx * qy - qw * qz);
    R[0][2] = 2.f * (qx * qz + qw * qy);
    R[1][0] = 2.f * (qx * qy + qw * qz);
    R[1][1] = 1.f - 2.f * (qx * qx + qz * qz);
    R[1][2] = 2.f * (qy * qz - qw * qx);
    R[2][0] = 2.f * (qx * qz - qw * qy);
    R[2][1] = 2.f * (qy * qz + qw * qx);
    R[2][2] = 1.f - 2.f * (qx * qx + qy * qy);

    float* ro = out + (size_t)b * 9;
#pragma unroll
    for (int i = 0; i < 3; ++i)
#pragma unroll
        for (int j = 0; j < 3; ++j)
            ro[3 * i + j] = R[i][j];

    float* to = out + (size_t)kB * 9 + (size_t)b * 3;
#pragma unroll
    for (int i = 0; i < 3; ++i)
        to[i] = cb[i] - (R[i][0] * ca[0] + R[i][1] * ca[1] + R[i][2] * ca[2]);
}

extern "C" void kernel_launch(void* const* d_in, const int* in_sizes, int n_in,
                              void* d_out, int out_size, void* d_ws, size_t ws_size,
                              hipStream_t stream) {
    const float* src      = (const float*)d_in[0];
    const float* src_corr = (const float*)d_in[1];
    const float* weights  = (const float*)d_in[2];
    float* out = (float*)d_out;
    wproc_kernel<<<kB, 256, 0, stream>>>(src, src_corr, weights, out);
}